// Round 7
// baseline (114.276 us; speedup 1.0000x reference)
//
#include <hip/hip_runtime.h>

// exp(K), K = skew(theta) 64x64.  Scheme (verified R6):
//   A = K * 2^-3 ;  T4(A) = I + A + A2/2 + A2*(A/6 + A2/24)  -- 2 matmuls
//   (B' = B^T = -A/6 + A2/24 stored so mm(A2,B') = A2*B = M);
//   then 3 squarings of E = R - I: (I+E)^2 = I + 2E + E^2, E fp32 in
//   regs (linear term exact), E^2 via single-bf16 MFMA.
// DUAL-INTERP: mfma(fwr[m],fwc[n]) = (PA*PB^T) col-own;
// mfma(fwc[i],fwr[j]) = (PA*PB^T) row-own -- same 8 frag reads serve
// both, so ER (row) and EC (col) planes get contiguous uint2 writes.
//
// R7 change: TWO matrices per 512-thread block (8 waves; waves 0-3 ->
// matrix 0, waves 4-7 -> matrix 1, separate 24KB LDS halves). R6 showed
// occupancy pinned at 38% (~3 blocks/CU) with VALU 55% / MFMA 18% --
// barrier-chained phases starved of co-resident waves. 48KB LDS -> 3
// blocks/CU = 24 waves (75%), double work per barrier.
// launch_bounds(512,6): VGPR cap 85 >= 52 used, no spill.

typedef short s16x8 __attribute__((ext_vector_type(8)));
typedef float f32x4 __attribute__((ext_vector_type(4)));
typedef unsigned int u32;
typedef unsigned short u16;

#define NTH 2016
#define MATSZ 24576
#define OFF_A    0
#define OFF_A2   8192
#define OFF_B    16384
#define OFF_ER   16384   // overlays B' (dead after mm2 frag reads)
#define OFF_EC   8192    // overlays A2 (dead after mm2 epilogue reads)
#define LDS_BYTES 49152

__device__ __forceinline__ u32 cvtpk(float a, float b) {  // lo=bf16(a), hi=bf16(b)
    u32 d;
    asm("v_cvt_pk_bf16_f32 %0, %1, %2" : "=v"(d) : "v"(a), "v"(b));
    return d;
}
__device__ __forceinline__ float bflo(u32 w) { return __builtin_bit_cast(float, w << 16); }
__device__ __forceinline__ float bfhi(u32 w) { return __builtin_bit_cast(float, w & 0xFFFF0000u); }
__device__ __forceinline__ float bf2f(u16 h) { return __builtin_bit_cast(float, (u32)h << 16); }
__device__ __forceinline__ s16x8 cast8(uint4 v) { return __builtin_bit_cast(s16x8, v); }
// swizzled byte offset: row r, byte-in-row bo (<128). XOR touches bits 4..6 only.
__device__ __forceinline__ int swz(int r, int bo) { return r * 128 + (bo ^ ((r & 7) << 4)); }

__global__ __launch_bounds__(512, 6)
void so_expm5(const float* __restrict__ theta, float* __restrict__ out) {
    __shared__ __align__(16) char sm_all[LDS_BYTES];
    const int tid = threadIdx.x;
    const int mat = tid >> 8;                    // 0/1: which matrix half
    char* sm = sm_all + mat * MATSZ;
    const int b = blockIdx.x * 2 + mat;
    const int t8 = tid & 255;                    // index within matrix's 4 waves
    const int l = tid & 63;
    const int w4 = (tid >> 6) & 3;               // wave index within matrix
    const int wr = w4 >> 1, wc = w4 & 1;
    const int q = l & 15, g = l >> 4;

    // ---- scatter: thread owns row=t8>>2, 16 cols; forward triangular map ----
    {
        const int row = t8 >> 2, cb = (t8 & 3) * 16;
        const float* th = theta + (size_t)b * NTH;
        const int offr = row * (127 - row) / 2;
        float v[16];
        #pragma unroll
        for (int k = 0; k < 16; ++k) {
            const int c = cb + k;
            const int au = offr + c - row - 1;              // upper: t-index of (row,c)
            const int al = c * (127 - c) / 2 + row - c - 1; // lower: t-index of (c,row)
            const int idx = (c > row) ? au : ((c < row) ? al : 0);
            const float t = th[idx];
            v[k] = ((c > row) ? -t : ((c < row) ? t : 0.f)) * 0.125f;   // A = K * 2^-3
        }
        #pragma unroll
        for (int k = 0; k < 4; ++k) {
            uint2 u;
            u.x = cvtpk(v[4 * k + 0], v[4 * k + 1]);
            u.y = cvtpk(v[4 * k + 2], v[4 * k + 3]);
            *reinterpret_cast<uint2*>(sm + OFF_A + swz(row, 2 * cb + 8 * k)) = u;
        }
    }
    __syncthreads();

    // frag loader: f[t][ks] = 8 bf16 (k-consec) from plane rows (rbase+16t+q)
    auto ld2 = [&](int plane, int rbase, s16x8 f[2][2]) {
        #pragma unroll
        for (int t = 0; t < 2; ++t) {
            const int r = rbase + 16 * t + q;
            const int a0 = swz(r, 16 * g);
            f[t][0] = cast8(*reinterpret_cast<const uint4*>(sm + plane + a0));
            f[t][1] = cast8(*reinterpret_cast<const uint4*>(sm + plane + (a0 ^ 64)));
        }
    };
    // col-ownership: ac[mt][nt] = (PA*PB^T)[32wr+16mt+4g+e][32wc+16nt+q]
    auto mm_col = [&](s16x8 fwr[2][2], s16x8 fwc[2][2], f32x4 ac[2][2]) {
        #pragma unroll
        for (int ks = 0; ks < 2; ++ks)
            #pragma unroll
            for (int mt = 0; mt < 2; ++mt)
                #pragma unroll
                for (int nt = 0; nt < 2; ++nt)
                    ac[mt][nt] = __builtin_amdgcn_mfma_f32_16x16x32_bf16(
                        fwr[mt][ks], fwc[nt][ks], ac[mt][nt], 0, 0, 0);
    };
    // row-ownership: ar[j][i] = (PA*PB^T)[32wr+16j+q][32wc+16i+4g+e]
    auto mm_row = [&](s16x8 fwr[2][2], s16x8 fwc[2][2], f32x4 ar[2][2]) {
        #pragma unroll
        for (int ks = 0; ks < 2; ++ks)
            #pragma unroll
            for (int j = 0; j < 2; ++j)
                #pragma unroll
                for (int i = 0; i < 2; ++i)
                    ar[j][i] = __builtin_amdgcn_mfma_f32_16x16x32_bf16(
                        fwc[i][ks], fwr[j][ks], ar[j][i], 0, 0, 0);
    };

    const f32x4 zf = {0.f, 0.f, 0.f, 0.f};
    s16x8 fwr[2][2], fwc[2][2];
    f32x4 ar[2][2], ac[2][2];

    // ---- mm1: ar = A*A^T = -A2 (row-own) ; write A2 and B' = -A/6 + A2/24 ----
    ar[0][0] = zf; ar[0][1] = zf; ar[1][0] = zf; ar[1][1] = zf;
    ld2(OFF_A, 32 * wr, fwr);
    ld2(OFF_A, 32 * wc, fwc);
    mm_row(fwr, fwc, ar);
    #pragma unroll
    for (int j = 0; j < 2; ++j)
        #pragma unroll
        for (int i = 0; i < 2; ++i) {
            const int r = 32 * wr + 16 * j + q, bo = 64 * wc + 32 * i + 8 * g;
            const uint2 ua = *reinterpret_cast<const uint2*>(sm + OFF_A + swz(r, bo));
            const float af[4] = {bflo(ua.x), bfhi(ua.x), bflo(ua.y), bfhi(ua.y)};
            float a2v[4], bv[4];
            #pragma unroll
            for (int e = 0; e < 4; ++e) {
                a2v[e] = -ar[j][i][e];
                bv[e]  = -af[e] * (1.f / 6.f) + a2v[e] * (1.f / 24.f);
            }
            uint2 w2, wb;
            w2.x = cvtpk(a2v[0], a2v[1]); w2.y = cvtpk(a2v[2], a2v[3]);
            wb.x = cvtpk(bv[0], bv[1]);   wb.y = cvtpk(bv[2], bv[3]);
            *reinterpret_cast<uint2*>(sm + OFF_A2 + swz(r, bo)) = w2;
            *reinterpret_cast<uint2*>(sm + OFF_B  + swz(r, bo)) = wb;
        }
    __syncthreads();

    // ---- mm2: M = A2*B'^T = A2*B (dual) ; E0 = A + A2/2 + M ----
    ar[0][0] = zf; ar[0][1] = zf; ar[1][0] = zf; ar[1][1] = zf;
    ac[0][0] = zf; ac[0][1] = zf; ac[1][0] = zf; ac[1][1] = zf;
    ld2(OFF_A2, 32 * wr, fwr);
    ld2(OFF_B, 32 * wc, fwc);
    mm_row(fwr, fwc, ar);
    mm_col(fwr, fwc, ac);
    float er_[2][2][4], ec_[2][2][4];
    // row state: positions [32wr+16j+q][32wc+16i+4g+e]
    #pragma unroll
    for (int j = 0; j < 2; ++j)
        #pragma unroll
        for (int i = 0; i < 2; ++i) {
            const int r = 32 * wr + 16 * j + q, bo = 64 * wc + 32 * i + 8 * g;
            const uint2 ua  = *reinterpret_cast<const uint2*>(sm + OFF_A  + swz(r, bo));
            const uint2 ua2 = *reinterpret_cast<const uint2*>(sm + OFF_A2 + swz(r, bo));
            const float af[4]  = {bflo(ua.x),  bfhi(ua.x),  bflo(ua.y),  bfhi(ua.y)};
            const float a2f[4] = {bflo(ua2.x), bfhi(ua2.x), bflo(ua2.y), bfhi(ua2.y)};
            #pragma unroll
            for (int e = 0; e < 4; ++e)
                er_[j][i][e] = af[e] + 0.5f * a2f[e] + ar[j][i][e];
        }
    // col state: positions [32wr+16mt+4g+e][32wc+16nt+q] (scattered b16 reads, once)
    #pragma unroll
    for (int mt = 0; mt < 2; ++mt)
        #pragma unroll
        for (int nt = 0; nt < 2; ++nt)
            #pragma unroll
            for (int e = 0; e < 4; ++e) {
                const int r = 32 * wr + 16 * mt + 4 * g + e;
                const int bo = 64 * wc + 32 * nt + 2 * q;
                const float af  = bf2f(*reinterpret_cast<const u16*>(sm + OFF_A  + swz(r, bo)));
                const float a2f = bf2f(*reinterpret_cast<const u16*>(sm + OFF_A2 + swz(r, bo)));
                ec_[mt][nt][e] = af + 0.5f * a2f + ac[mt][nt][e];
            }
    __syncthreads();   // frag reads of B' and epi reads of A2 done before overlay
    #pragma unroll
    for (int j = 0; j < 2; ++j)
        #pragma unroll
        for (int i = 0; i < 2; ++i) {
            const int r = 32 * wr + 16 * j + q, bo = 64 * wc + 32 * i + 8 * g;
            uint2 w;
            w.x = cvtpk(er_[j][i][0], er_[j][i][1]);
            w.y = cvtpk(er_[j][i][2], er_[j][i][3]);
            *reinterpret_cast<uint2*>(sm + OFF_ER + swz(r, bo)) = w;
            const int rc = 32 * wc + 16 * i + q, boc = 64 * wr + 32 * j + 8 * g;
            uint2 wcv;
            wcv.x = cvtpk(ec_[j][i][0], ec_[j][i][1]);   // ec_ indexed [mt][nt]
            wcv.y = cvtpk(ec_[j][i][2], ec_[j][i][3]);
            *reinterpret_cast<uint2*>(sm + OFF_EC + swz(rc, boc)) = wcv;
        }
    __syncthreads();

    // ---- 2 squarings: E <- 2E + E^2, dual ownership, shared frags ----
    #pragma unroll 1
    for (int sq = 0; sq < 2; ++sq) {
        ar[0][0] = zf; ar[0][1] = zf; ar[1][0] = zf; ar[1][1] = zf;
        ac[0][0] = zf; ac[0][1] = zf; ac[1][0] = zf; ac[1][1] = zf;
        ld2(OFF_ER, 32 * wr, fwr);
        ld2(OFF_EC, 32 * wc, fwc);
        mm_row(fwr, fwc, ar);   // E^2 row-own  (ER*EC^T = E*E)
        mm_col(fwr, fwc, ac);   // E^2 col-own
        #pragma unroll
        for (int j = 0; j < 2; ++j)
            #pragma unroll
            for (int i = 0; i < 2; ++i)
                #pragma unroll
                for (int e = 0; e < 4; ++e) {
                    er_[j][i][e] = 2.f * er_[j][i][e] + ar[j][i][e];
                    ec_[j][i][e] = 2.f * ec_[j][i][e] + ac[j][i][e];
                }
        __syncthreads();
        #pragma unroll
        for (int j = 0; j < 2; ++j)
            #pragma unroll
            for (int i = 0; i < 2; ++i) {
                const int r = 32 * wr + 16 * j + q, bo = 64 * wc + 32 * i + 8 * g;
                uint2 w;
                w.x = cvtpk(er_[j][i][0], er_[j][i][1]);
                w.y = cvtpk(er_[j][i][2], er_[j][i][3]);
                *reinterpret_cast<uint2*>(sm + OFF_ER + swz(r, bo)) = w;
                const int rc = 32 * wc + 16 * i + q, boc = 64 * wr + 32 * j + 8 * g;
                uint2 wcv;
                wcv.x = cvtpk(ec_[j][i][0], ec_[j][i][1]);
                wcv.y = cvtpk(ec_[j][i][2], ec_[j][i][3]);
                *reinterpret_cast<uint2*>(sm + OFF_EC + swz(rc, boc)) = wcv;
            }
        __syncthreads();
    }

    // ---- 3rd squaring: row-own only, straight to global (float4) ----
    ar[0][0] = zf; ar[0][1] = zf; ar[1][0] = zf; ar[1][1] = zf;
    ld2(OFF_ER, 32 * wr, fwr);
    ld2(OFF_EC, 32 * wc, fwc);
    mm_row(fwr, fwc, ar);
    float* op = out + (size_t)b * 4096;
    #pragma unroll
    for (int j = 0; j < 2; ++j)
        #pragma unroll
        for (int i = 0; i < 2; ++i) {
            const int r = 32 * wr + 16 * j + q, c0 = 32 * wc + 16 * i + 4 * g;
            float4 o;
            o.x = ((r == c0 + 0) ? 1.f : 0.f) + 2.f * er_[j][i][0] + ar[j][i][0];
            o.y = ((r == c0 + 1) ? 1.f : 0.f) + 2.f * er_[j][i][1] + ar[j][i][1];
            o.z = ((r == c0 + 2) ? 1.f : 0.f) + 2.f * er_[j][i][2] + ar[j][i][2];
            o.w = ((r == c0 + 3) ? 1.f : 0.f) + 2.f * er_[j][i][3] + ar[j][i][3];
            *reinterpret_cast<float4*>(op + r * 64 + c0) = o;
        }
}

extern "C" void kernel_launch(void* const* d_in, const int* in_sizes, int n_in,
                              void* d_out, int out_size, void* d_ws, size_t ws_size,
                              hipStream_t stream) {
    const float* theta = (const float*)d_in[0];
    float* out = (float*)d_out;
    const int nbatch = in_sizes[0] / NTH;   // 8192
    so_expm5<<<nbatch / 2, 512, 0, stream>>>(theta, out);
}

// Round 8
// 71.776 us; speedup vs baseline: 1.5921x; 1.5921x over previous
//
#include <hip/hip_runtime.h>

// exp(K), K = skew(theta) 64x64.  Scheme (verified R6):
//   A = K * 2^-3 ;  T4(A) = I + A + A2/2 + A2*(A/6 + A2/24)  -- 2 matmuls
//   (B' = B^T = -A/6 + A2/24 stored so mm(A2,B') = A2*B = M);
//   then 3 squarings of E = R - I: (I+E)^2 = I + 2E + E^2, E fp32 in
//   regs (linear term exact), E^2 via single-bf16 MFMA.
// DUAL-INTERP: mfma(fwr[m],fwc[n]) = (PA*PB^T) col-own;
// mfma(fwc[i],fwr[j]) = (PA*PB^T) row-own -- same 8 frag reads serve
// both, so ER (row) and EC (col) planes get contiguous uint2 writes.
//
// TWO matrices per 512-thread block (waves 0-3 -> matrix 0, waves 4-7 ->
// matrix 1, separate 24KB LDS halves); 48KB LDS -> 3 blocks/CU = 24
// waves (75% ceiling), double work per barrier.
// R8 fix: launch_bounds(512,4) not (512,6). R7's (512,6) capped VGPRs
// at ~85, allocator settled at 40 + SPILL (FETCH 125MB/WRITE 370MB vs
// 33/131 ideal) -- same failure as R3. (512,4) gives cap 128 >= 52
// live; occupancy is then LDS-limited at 6 waves/EU anyway.

typedef short s16x8 __attribute__((ext_vector_type(8)));
typedef float f32x4 __attribute__((ext_vector_type(4)));
typedef unsigned int u32;
typedef unsigned short u16;

#define NTH 2016
#define MATSZ 24576
#define OFF_A    0
#define OFF_A2   8192
#define OFF_B    16384
#define OFF_ER   16384   // overlays B' (dead after mm2 frag reads)
#define OFF_EC   8192    // overlays A2 (dead after mm2 epilogue reads)
#define LDS_BYTES 49152

__device__ __forceinline__ u32 cvtpk(float a, float b) {  // lo=bf16(a), hi=bf16(b)
    u32 d;
    asm("v_cvt_pk_bf16_f32 %0, %1, %2" : "=v"(d) : "v"(a), "v"(b));
    return d;
}
__device__ __forceinline__ float bflo(u32 w) { return __builtin_bit_cast(float, w << 16); }
__device__ __forceinline__ float bfhi(u32 w) { return __builtin_bit_cast(float, w & 0xFFFF0000u); }
__device__ __forceinline__ float bf2f(u16 h) { return __builtin_bit_cast(float, (u32)h << 16); }
__device__ __forceinline__ s16x8 cast8(uint4 v) { return __builtin_bit_cast(s16x8, v); }
// swizzled byte offset: row r, byte-in-row bo (<128). XOR touches bits 4..6 only.
__device__ __forceinline__ int swz(int r, int bo) { return r * 128 + (bo ^ ((r & 7) << 4)); }

__global__ __launch_bounds__(512, 4)
void so_expm6(const float* __restrict__ theta, float* __restrict__ out) {
    __shared__ __align__(16) char sm_all[LDS_BYTES];
    const int tid = threadIdx.x;
    const int mat = tid >> 8;                    // 0/1: which matrix half
    char* sm = sm_all + mat * MATSZ;
    const int b = blockIdx.x * 2 + mat;
    const int t8 = tid & 255;                    // index within matrix's 4 waves
    const int l = tid & 63;
    const int w4 = (tid >> 6) & 3;               // wave index within matrix
    const int wr = w4 >> 1, wc = w4 & 1;
    const int q = l & 15, g = l >> 4;

    // ---- scatter: thread owns row=t8>>2, 16 cols; forward triangular map ----
    {
        const int row = t8 >> 2, cb = (t8 & 3) * 16;
        const float* th = theta + (size_t)b * NTH;
        const int offr = row * (127 - row) / 2;
        float v[16];
        #pragma unroll
        for (int k = 0; k < 16; ++k) {
            const int c = cb + k;
            const int au = offr + c - row - 1;              // upper: t-index of (row,c)
            const int al = c * (127 - c) / 2 + row - c - 1; // lower: t-index of (c,row)
            const int idx = (c > row) ? au : ((c < row) ? al : 0);
            const float t = th[idx];
            v[k] = ((c > row) ? -t : ((c < row) ? t : 0.f)) * 0.125f;   // A = K * 2^-3
        }
        #pragma unroll
        for (int k = 0; k < 4; ++k) {
            uint2 u;
            u.x = cvtpk(v[4 * k + 0], v[4 * k + 1]);
            u.y = cvtpk(v[4 * k + 2], v[4 * k + 3]);
            *reinterpret_cast<uint2*>(sm + OFF_A + swz(row, 2 * cb + 8 * k)) = u;
        }
    }
    __syncthreads();

    // frag loader: f[t][ks] = 8 bf16 (k-consec) from plane rows (rbase+16t+q)
    auto ld2 = [&](int plane, int rbase, s16x8 f[2][2]) {
        #pragma unroll
        for (int t = 0; t < 2; ++t) {
            const int r = rbase + 16 * t + q;
            const int a0 = swz(r, 16 * g);
            f[t][0] = cast8(*reinterpret_cast<const uint4*>(sm + plane + a0));
            f[t][1] = cast8(*reinterpret_cast<const uint4*>(sm + plane + (a0 ^ 64)));
        }
    };
    // col-ownership: ac[mt][nt] = (PA*PB^T)[32wr+16mt+4g+e][32wc+16nt+q]
    auto mm_col = [&](s16x8 fwr[2][2], s16x8 fwc[2][2], f32x4 ac[2][2]) {
        #pragma unroll
        for (int ks = 0; ks < 2; ++ks)
            #pragma unroll
            for (int mt = 0; mt < 2; ++mt)
                #pragma unroll
                for (int nt = 0; nt < 2; ++nt)
                    ac[mt][nt] = __builtin_amdgcn_mfma_f32_16x16x32_bf16(
                        fwr[mt][ks], fwc[nt][ks], ac[mt][nt], 0, 0, 0);
    };
    // row-ownership: ar[j][i] = (PA*PB^T)[32wr+16j+q][32wc+16i+4g+e]
    auto mm_row = [&](s16x8 fwr[2][2], s16x8 fwc[2][2], f32x4 ar[2][2]) {
        #pragma unroll
        for (int ks = 0; ks < 2; ++ks)
            #pragma unroll
            for (int j = 0; j < 2; ++j)
                #pragma unroll
                for (int i = 0; i < 2; ++i)
                    ar[j][i] = __builtin_amdgcn_mfma_f32_16x16x32_bf16(
                        fwc[i][ks], fwr[j][ks], ar[j][i], 0, 0, 0);
    };

    const f32x4 zf = {0.f, 0.f, 0.f, 0.f};
    s16x8 fwr[2][2], fwc[2][2];
    f32x4 ar[2][2], ac[2][2];

    // ---- mm1: ar = A*A^T = -A2 (row-own) ; write A2 and B' = -A/6 + A2/24 ----
    ar[0][0] = zf; ar[0][1] = zf; ar[1][0] = zf; ar[1][1] = zf;
    ld2(OFF_A, 32 * wr, fwr);
    ld2(OFF_A, 32 * wc, fwc);
    mm_row(fwr, fwc, ar);
    #pragma unroll
    for (int j = 0; j < 2; ++j)
        #pragma unroll
        for (int i = 0; i < 2; ++i) {
            const int r = 32 * wr + 16 * j + q, bo = 64 * wc + 32 * i + 8 * g;
            const uint2 ua = *reinterpret_cast<const uint2*>(sm + OFF_A + swz(r, bo));
            const float af[4] = {bflo(ua.x), bfhi(ua.x), bflo(ua.y), bfhi(ua.y)};
            float a2v[4], bv[4];
            #pragma unroll
            for (int e = 0; e < 4; ++e) {
                a2v[e] = -ar[j][i][e];
                bv[e]  = -af[e] * (1.f / 6.f) + a2v[e] * (1.f / 24.f);
            }
            uint2 w2, wb;
            w2.x = cvtpk(a2v[0], a2v[1]); w2.y = cvtpk(a2v[2], a2v[3]);
            wb.x = cvtpk(bv[0], bv[1]);   wb.y = cvtpk(bv[2], bv[3]);
            *reinterpret_cast<uint2*>(sm + OFF_A2 + swz(r, bo)) = w2;
            *reinterpret_cast<uint2*>(sm + OFF_B  + swz(r, bo)) = wb;
        }
    __syncthreads();

    // ---- mm2: M = A2*B'^T = A2*B (dual) ; E0 = A + A2/2 + M ----
    ar[0][0] = zf; ar[0][1] = zf; ar[1][0] = zf; ar[1][1] = zf;
    ac[0][0] = zf; ac[0][1] = zf; ac[1][0] = zf; ac[1][1] = zf;
    ld2(OFF_A2, 32 * wr, fwr);
    ld2(OFF_B, 32 * wc, fwc);
    mm_row(fwr, fwc, ar);
    mm_col(fwr, fwc, ac);
    float er_[2][2][4], ec_[2][2][4];
    // row state: positions [32wr+16j+q][32wc+16i+4g+e]
    #pragma unroll
    for (int j = 0; j < 2; ++j)
        #pragma unroll
        for (int i = 0; i < 2; ++i) {
            const int r = 32 * wr + 16 * j + q, bo = 64 * wc + 32 * i + 8 * g;
            const uint2 ua  = *reinterpret_cast<const uint2*>(sm + OFF_A  + swz(r, bo));
            const uint2 ua2 = *reinterpret_cast<const uint2*>(sm + OFF_A2 + swz(r, bo));
            const float af[4]  = {bflo(ua.x),  bfhi(ua.x),  bflo(ua.y),  bfhi(ua.y)};
            const float a2f[4] = {bflo(ua2.x), bfhi(ua2.x), bflo(ua2.y), bfhi(ua2.y)};
            #pragma unroll
            for (int e = 0; e < 4; ++e)
                er_[j][i][e] = af[e] + 0.5f * a2f[e] + ar[j][i][e];
        }
    // col state: positions [32wr+16mt+4g+e][32wc+16nt+q] (scattered b16 reads, once)
    #pragma unroll
    for (int mt = 0; mt < 2; ++mt)
        #pragma unroll
        for (int nt = 0; nt < 2; ++nt)
            #pragma unroll
            for (int e = 0; e < 4; ++e) {
                const int r = 32 * wr + 16 * mt + 4 * g + e;
                const int bo = 64 * wc + 32 * nt + 2 * q;
                const float af  = bf2f(*reinterpret_cast<const u16*>(sm + OFF_A  + swz(r, bo)));
                const float a2f = bf2f(*reinterpret_cast<const u16*>(sm + OFF_A2 + swz(r, bo)));
                ec_[mt][nt][e] = af + 0.5f * a2f + ac[mt][nt][e];
            }
    __syncthreads();   // frag reads of B' and epi reads of A2 done before overlay
    #pragma unroll
    for (int j = 0; j < 2; ++j)
        #pragma unroll
        for (int i = 0; i < 2; ++i) {
            const int r = 32 * wr + 16 * j + q, bo = 64 * wc + 32 * i + 8 * g;
            uint2 w;
            w.x = cvtpk(er_[j][i][0], er_[j][i][1]);
            w.y = cvtpk(er_[j][i][2], er_[j][i][3]);
            *reinterpret_cast<uint2*>(sm + OFF_ER + swz(r, bo)) = w;
            const int rc = 32 * wc + 16 * i + q, boc = 64 * wr + 32 * j + 8 * g;
            uint2 wcv;
            wcv.x = cvtpk(ec_[j][i][0], ec_[j][i][1]);   // ec_ indexed [mt][nt]
            wcv.y = cvtpk(ec_[j][i][2], ec_[j][i][3]);
            *reinterpret_cast<uint2*>(sm + OFF_EC + swz(rc, boc)) = wcv;
        }
    __syncthreads();

    // ---- 2 squarings: E <- 2E + E^2, dual ownership, shared frags ----
    #pragma unroll 1
    for (int sq = 0; sq < 2; ++sq) {
        ar[0][0] = zf; ar[0][1] = zf; ar[1][0] = zf; ar[1][1] = zf;
        ac[0][0] = zf; ac[0][1] = zf; ac[1][0] = zf; ac[1][1] = zf;
        ld2(OFF_ER, 32 * wr, fwr);
        ld2(OFF_EC, 32 * wc, fwc);
        mm_row(fwr, fwc, ar);   // E^2 row-own  (ER*EC^T = E*E)
        mm_col(fwr, fwc, ac);   // E^2 col-own
        #pragma unroll
        for (int j = 0; j < 2; ++j)
            #pragma unroll
            for (int i = 0; i < 2; ++i)
                #pragma unroll
                for (int e = 0; e < 4; ++e) {
                    er_[j][i][e] = 2.f * er_[j][i][e] + ar[j][i][e];
                    ec_[j][i][e] = 2.f * ec_[j][i][e] + ac[j][i][e];
                }
        __syncthreads();
        #pragma unroll
        for (int j = 0; j < 2; ++j)
            #pragma unroll
            for (int i = 0; i < 2; ++i) {
                const int r = 32 * wr + 16 * j + q, bo = 64 * wc + 32 * i + 8 * g;
                uint2 w;
                w.x = cvtpk(er_[j][i][0], er_[j][i][1]);
                w.y = cvtpk(er_[j][i][2], er_[j][i][3]);
                *reinterpret_cast<uint2*>(sm + OFF_ER + swz(r, bo)) = w;
                const int rc = 32 * wc + 16 * i + q, boc = 64 * wr + 32 * j + 8 * g;
                uint2 wcv;
                wcv.x = cvtpk(ec_[j][i][0], ec_[j][i][1]);
                wcv.y = cvtpk(ec_[j][i][2], ec_[j][i][3]);
                *reinterpret_cast<uint2*>(sm + OFF_EC + swz(rc, boc)) = wcv;
            }
        __syncthreads();
    }

    // ---- 3rd squaring: row-own only, straight to global (float4) ----
    ar[0][0] = zf; ar[0][1] = zf; ar[1][0] = zf; ar[1][1] = zf;
    ld2(OFF_ER, 32 * wr, fwr);
    ld2(OFF_EC, 32 * wc, fwc);
    mm_row(fwr, fwc, ar);
    float* op = out + (size_t)b * 4096;
    #pragma unroll
    for (int j = 0; j < 2; ++j)
        #pragma unroll
        for (int i = 0; i < 2; ++i) {
            const int r = 32 * wr + 16 * j + q, c0 = 32 * wc + 16 * i + 4 * g;
            float4 o;
            o.x = ((r == c0 + 0) ? 1.f : 0.f) + 2.f * er_[j][i][0] + ar[j][i][0];
            o.y = ((r == c0 + 1) ? 1.f : 0.f) + 2.f * er_[j][i][1] + ar[j][i][1];
            o.z = ((r == c0 + 2) ? 1.f : 0.f) + 2.f * er_[j][i][2] + ar[j][i][2];
            o.w = ((r == c0 + 3) ? 1.f : 0.f) + 2.f * er_[j][i][3] + ar[j][i][3];
            *reinterpret_cast<float4*>(op + r * 64 + c0) = o;
        }
}

extern "C" void kernel_launch(void* const* d_in, const int* in_sizes, int n_in,
                              void* d_out, int out_size, void* d_ws, size_t ws_size,
                              hipStream_t stream) {
    const float* theta = (const float*)d_in[0];
    float* out = (float*)d_out;
    const int nbatch = in_sizes[0] / NTH;   // 8192
    so_expm6<<<nbatch / 2, 512, 0, stream>>>(theta, out);
}

// Round 9
// 65.627 us; speedup vs baseline: 1.7413x; 1.0937x over previous
//
#include <hip/hip_runtime.h>

// exp(K), K = skew(theta) 64x64.  Scheme (verified R6):
//   A = K * 2^-3 ;  T4(A) = I + A + A2/2 + A2*(A/6 + A2/24)  -- 2 matmuls
//   (B' = B^T = -A/6 + A2/24 stored so mm(A2,B') = A2*B = M);
//   then 3 squarings of E = R - I: (I+E)^2 = I + 2E + E^2, E fp32 in
//   regs (linear term exact), E^2 via single-bf16 MFMA.
// DUAL-INTERP: mfma(fwr[m],fwc[n]) = (PA*PB^T) col-own;
// mfma(fwc[i],fwr[j]) = (PA*PB^T) row-own -- same 8 frag reads serve
// both, so ER (row) and EC (col) planes get contiguous uint2 writes.
//
// R9 change: PING-PONG PLANES to cut barriers 8 -> 5. R8 falsified the
// occupancy lever (pinned ~12 waves/CU across 24/32/48KB LDS); the cost
// is the barrier-serialized phase chain. With 5 planes (40KB: A, A2, B,
// E0R, E0C) every phase writes FRESH planes, so the pre-write barrier
// goes away: one sync per phase (scatter, mm1, mm2, sq0, sq1; final
// squaring streams to global, no sync). 256-thread 1-matrix blocks
// (R8's 2-matrix packing was neutral-to-worse -- reverted).
// launch_bounds(256,4): VGPR cap 128 >= ~56 live, no spill (R3/R7 rule).

typedef short s16x8 __attribute__((ext_vector_type(8)));
typedef float f32x4 __attribute__((ext_vector_type(4)));
typedef unsigned int u32;
typedef unsigned short u16;

#define NTH 2016
#define OFF_A    0
#define OFF_A2   8192
#define OFF_B    16384
#define OFF_E0R  24576
#define OFF_E0C  32768
#define LDS_BYTES 40960

__device__ __forceinline__ u32 cvtpk(float a, float b) {  // lo=bf16(a), hi=bf16(b)
    u32 d;
    asm("v_cvt_pk_bf16_f32 %0, %1, %2" : "=v"(d) : "v"(a), "v"(b));
    return d;
}
__device__ __forceinline__ float bflo(u32 w) { return __builtin_bit_cast(float, w << 16); }
__device__ __forceinline__ float bfhi(u32 w) { return __builtin_bit_cast(float, w & 0xFFFF0000u); }
__device__ __forceinline__ float bf2f(u16 h) { return __builtin_bit_cast(float, (u32)h << 16); }
__device__ __forceinline__ s16x8 cast8(uint4 v) { return __builtin_bit_cast(s16x8, v); }
// swizzled byte offset: row r, byte-in-row bo (<128). XOR touches bits 4..6 only.
__device__ __forceinline__ int swz(int r, int bo) { return r * 128 + (bo ^ ((r & 7) << 4)); }

__global__ __launch_bounds__(256, 4)
void so_expm7(const float* __restrict__ theta, float* __restrict__ out) {
    __shared__ __align__(16) char sm[LDS_BYTES];
    const int tid = threadIdx.x;
    const int b   = blockIdx.x;
    const int l = tid & 63;
    const int w4 = tid >> 6;
    const int wr = w4 >> 1, wc = w4 & 1;
    const int q = l & 15, g = l >> 4;

    // ---- scatter: thread owns row=tid>>2, 16 cols; forward triangular map ----
    {
        const int row = tid >> 2, cb = (tid & 3) * 16;
        const float* th = theta + (size_t)b * NTH;
        const int offr = row * (127 - row) / 2;
        float v[16];
        #pragma unroll
        for (int k = 0; k < 16; ++k) {
            const int c = cb + k;
            const int au = offr + c - row - 1;              // upper: t-index of (row,c)
            const int al = c * (127 - c) / 2 + row - c - 1; // lower: t-index of (c,row)
            const int idx = (c > row) ? au : ((c < row) ? al : 0);
            const float t = th[idx];
            v[k] = ((c > row) ? -t : ((c < row) ? t : 0.f)) * 0.125f;   // A = K * 2^-3
        }
        #pragma unroll
        for (int k = 0; k < 4; ++k) {
            uint2 u;
            u.x = cvtpk(v[4 * k + 0], v[4 * k + 1]);
            u.y = cvtpk(v[4 * k + 2], v[4 * k + 3]);
            *reinterpret_cast<uint2*>(sm + OFF_A + swz(row, 2 * cb + 8 * k)) = u;
        }
    }
    __syncthreads();   // (1)

    // frag loader: f[t][ks] = 8 bf16 (k-consec) from plane rows (rbase+16t+q)
    auto ld2 = [&](int plane, int rbase, s16x8 f[2][2]) {
        #pragma unroll
        for (int t = 0; t < 2; ++t) {
            const int r = rbase + 16 * t + q;
            const int a0 = swz(r, 16 * g);
            f[t][0] = cast8(*reinterpret_cast<const uint4*>(sm + plane + a0));
            f[t][1] = cast8(*reinterpret_cast<const uint4*>(sm + plane + (a0 ^ 64)));
        }
    };
    // col-ownership: ac[mt][nt] = (PA*PB^T)[32wr+16mt+4g+e][32wc+16nt+q]
    auto mm_col = [&](s16x8 fwr[2][2], s16x8 fwc[2][2], f32x4 ac[2][2]) {
        #pragma unroll
        for (int ks = 0; ks < 2; ++ks)
            #pragma unroll
            for (int mt = 0; mt < 2; ++mt)
                #pragma unroll
                for (int nt = 0; nt < 2; ++nt)
                    ac[mt][nt] = __builtin_amdgcn_mfma_f32_16x16x32_bf16(
                        fwr[mt][ks], fwc[nt][ks], ac[mt][nt], 0, 0, 0);
    };
    // row-ownership: ar[j][i] = (PA*PB^T)[32wr+16j+q][32wc+16i+4g+e]
    auto mm_row = [&](s16x8 fwr[2][2], s16x8 fwc[2][2], f32x4 ar[2][2]) {
        #pragma unroll
        for (int ks = 0; ks < 2; ++ks)
            #pragma unroll
            for (int j = 0; j < 2; ++j)
                #pragma unroll
                for (int i = 0; i < 2; ++i)
                    ar[j][i] = __builtin_amdgcn_mfma_f32_16x16x32_bf16(
                        fwc[i][ks], fwr[j][ks], ar[j][i], 0, 0, 0);
    };

    const f32x4 zf = {0.f, 0.f, 0.f, 0.f};
    s16x8 fwr[2][2], fwc[2][2];
    f32x4 ar[2][2], ac[2][2];
    float er_[2][2][4], ec_[2][2][4];

    // ---- mm1: ar = A*A^T = -A2 (row-own) ; write A2 and B' = -A/6 + A2/24 ----
    ar[0][0] = zf; ar[0][1] = zf; ar[1][0] = zf; ar[1][1] = zf;
    ld2(OFF_A, 32 * wr, fwr);
    ld2(OFF_A, 32 * wc, fwc);
    mm_row(fwr, fwc, ar);
    #pragma unroll
    for (int j = 0; j < 2; ++j)
        #pragma unroll
        for (int i = 0; i < 2; ++i) {
            const int r = 32 * wr + 16 * j + q, bo = 64 * wc + 32 * i + 8 * g;
            const uint2 ua = *reinterpret_cast<const uint2*>(sm + OFF_A + swz(r, bo));
            const float af[4] = {bflo(ua.x), bfhi(ua.x), bflo(ua.y), bfhi(ua.y)};
            float a2v[4], bv[4];
            #pragma unroll
            for (int e = 0; e < 4; ++e) {
                a2v[e] = -ar[j][i][e];
                bv[e]  = -af[e] * (1.f / 6.f) + a2v[e] * (1.f / 24.f);
            }
            uint2 w2, wb;
            w2.x = cvtpk(a2v[0], a2v[1]); w2.y = cvtpk(a2v[2], a2v[3]);
            wb.x = cvtpk(bv[0], bv[1]);   wb.y = cvtpk(bv[2], bv[3]);
            *reinterpret_cast<uint2*>(sm + OFF_A2 + swz(r, bo)) = w2;
            *reinterpret_cast<uint2*>(sm + OFF_B  + swz(r, bo)) = wb;
        }
    __syncthreads();   // (2)

    // ---- mm2: M = A2*B'^T = A2*B (dual) ; E0 = A + A2/2 + M -> E0R/E0C (fresh) ----
    ar[0][0] = zf; ar[0][1] = zf; ar[1][0] = zf; ar[1][1] = zf;
    ac[0][0] = zf; ac[0][1] = zf; ac[1][0] = zf; ac[1][1] = zf;
    ld2(OFF_A2, 32 * wr, fwr);
    ld2(OFF_B, 32 * wc, fwc);
    mm_row(fwr, fwc, ar);
    mm_col(fwr, fwc, ac);
    // row state: positions [32wr+16j+q][32wc+16i+4g+e]
    #pragma unroll
    for (int j = 0; j < 2; ++j)
        #pragma unroll
        for (int i = 0; i < 2; ++i) {
            const int r = 32 * wr + 16 * j + q, bo = 64 * wc + 32 * i + 8 * g;
            const uint2 ua  = *reinterpret_cast<const uint2*>(sm + OFF_A  + swz(r, bo));
            const uint2 ua2 = *reinterpret_cast<const uint2*>(sm + OFF_A2 + swz(r, bo));
            const float af[4]  = {bflo(ua.x),  bfhi(ua.x),  bflo(ua.y),  bfhi(ua.y)};
            const float a2f[4] = {bflo(ua2.x), bfhi(ua2.x), bflo(ua2.y), bfhi(ua2.y)};
            #pragma unroll
            for (int e = 0; e < 4; ++e)
                er_[j][i][e] = af[e] + 0.5f * a2f[e] + ar[j][i][e];
        }
    // col state: positions [32wr+16mt+4g+e][32wc+16nt+q] (scattered b16 reads, once)
    #pragma unroll
    for (int mt = 0; mt < 2; ++mt)
        #pragma unroll
        for (int nt = 0; nt < 2; ++nt)
            #pragma unroll
            for (int e = 0; e < 4; ++e) {
                const int r = 32 * wr + 16 * mt + 4 * g + e;
                const int bo = 64 * wc + 32 * nt + 2 * q;
                const float af  = bf2f(*reinterpret_cast<const u16*>(sm + OFF_A  + swz(r, bo)));
                const float a2f = bf2f(*reinterpret_cast<const u16*>(sm + OFF_A2 + swz(r, bo)));
                ec_[mt][nt][e] = af + 0.5f * a2f + ac[mt][nt][e];
            }
    // write E0 to FRESH planes -- no pre-write barrier needed
    #pragma unroll
    for (int j = 0; j < 2; ++j)
        #pragma unroll
        for (int i = 0; i < 2; ++i) {
            const int r = 32 * wr + 16 * j + q, bo = 64 * wc + 32 * i + 8 * g;
            uint2 w;
            w.x = cvtpk(er_[j][i][0], er_[j][i][1]);
            w.y = cvtpk(er_[j][i][2], er_[j][i][3]);
            *reinterpret_cast<uint2*>(sm + OFF_E0R + swz(r, bo)) = w;
            const int rc = 32 * wc + 16 * i + q, boc = 64 * wr + 32 * j + 8 * g;
            uint2 wcv;
            wcv.x = cvtpk(ec_[j][i][0], ec_[j][i][1]);   // ec_ indexed [mt][nt]
            wcv.y = cvtpk(ec_[j][i][2], ec_[j][i][3]);
            *reinterpret_cast<uint2*>(sm + OFF_E0C + swz(rc, boc)) = wcv;
        }
    __syncthreads();   // (3)

    // squaring: read (RDR,RDC), E <- 2E + E^2, write (WRR,WRC) [fresh], one sync
    auto do_square = [&](int RDR, int RDC, int WRR, int WRC) {
        ar[0][0] = zf; ar[0][1] = zf; ar[1][0] = zf; ar[1][1] = zf;
        ac[0][0] = zf; ac[0][1] = zf; ac[1][0] = zf; ac[1][1] = zf;
        ld2(RDR, 32 * wr, fwr);
        ld2(RDC, 32 * wc, fwc);
        mm_row(fwr, fwc, ar);   // E^2 row-own  (ER*EC^T = E*E)
        mm_col(fwr, fwc, ac);   // E^2 col-own
        #pragma unroll
        for (int j = 0; j < 2; ++j)
            #pragma unroll
            for (int i = 0; i < 2; ++i)
                #pragma unroll
                for (int e = 0; e < 4; ++e) {
                    er_[j][i][e] = 2.f * er_[j][i][e] + ar[j][i][e];
                    ec_[j][i][e] = 2.f * ec_[j][i][e] + ac[j][i][e];
                }
        #pragma unroll
        for (int j = 0; j < 2; ++j)
            #pragma unroll
            for (int i = 0; i < 2; ++i) {
                const int r = 32 * wr + 16 * j + q, bo = 64 * wc + 32 * i + 8 * g;
                uint2 w;
                w.x = cvtpk(er_[j][i][0], er_[j][i][1]);
                w.y = cvtpk(er_[j][i][2], er_[j][i][3]);
                *reinterpret_cast<uint2*>(sm + WRR + swz(r, bo)) = w;
                const int rc = 32 * wc + 16 * i + q, boc = 64 * wr + 32 * j + 8 * g;
                uint2 wcv;
                wcv.x = cvtpk(ec_[j][i][0], ec_[j][i][1]);
                wcv.y = cvtpk(ec_[j][i][2], ec_[j][i][3]);
                *reinterpret_cast<uint2*>(sm + WRC + swz(rc, boc)) = wcv;
            }
        __syncthreads();
    };

    do_square(OFF_E0R, OFF_E0C, OFF_B, OFF_A2);   // sq0 -> (B, A2)   sync (4)
    do_square(OFF_B, OFF_A2, OFF_E0R, OFF_E0C);   // sq1 -> (E0R,E0C) sync (5)

    // ---- 3rd squaring: row-own only, straight to global (float4), no sync ----
    ar[0][0] = zf; ar[0][1] = zf; ar[1][0] = zf; ar[1][1] = zf;
    ld2(OFF_E0R, 32 * wr, fwr);
    ld2(OFF_E0C, 32 * wc, fwc);
    mm_row(fwr, fwc, ar);
    float* op = out + (size_t)b * 4096;
    #pragma unroll
    for (int j = 0; j < 2; ++j)
        #pragma unroll
        for (int i = 0; i < 2; ++i) {
            const int r = 32 * wr + 16 * j + q, c0 = 32 * wc + 16 * i + 4 * g;
            float4 o;
            o.x = ((r == c0 + 0) ? 1.f : 0.f) + 2.f * er_[j][i][0] + ar[j][i][0];
            o.y = ((r == c0 + 1) ? 1.f : 0.f) + 2.f * er_[j][i][1] + ar[j][i][1];
            o.z = ((r == c0 + 2) ? 1.f : 0.f) + 2.f * er_[j][i][2] + ar[j][i][2];
            o.w = ((r == c0 + 3) ? 1.f : 0.f) + 2.f * er_[j][i][3] + ar[j][i][3];
            *reinterpret_cast<float4*>(op + r * 64 + c0) = o;
        }
}

extern "C" void kernel_launch(void* const* d_in, const int* in_sizes, int n_in,
                              void* d_out, int out_size, void* d_ws, size_t ws_size,
                              hipStream_t stream) {
    const float* theta = (const float*)d_in[0];
    float* out = (float*)d_out;
    const int nbatch = in_sizes[0] / NTH;   // 8192
    so_expm7<<<nbatch, 256, 0, stream>>>(theta, out);
}